// Round 18
// baseline (342.107 us; speedup 1.0000x reference)
//
#include <hip/hip_runtime.h>

#define TTOK 2048
#define HIDN 4096
#define OPD  6144
#define DH   128
#define VD   256
#define KOFF 4096
#define VOFF 5120

typedef short  s16x8 __attribute__((ext_vector_type(8)));
typedef unsigned short u16x8 __attribute__((ext_vector_type(8)));
typedef float  fx4   __attribute__((ext_vector_type(4)));

constexpr float LAM_INIT = 0.7455692280263534f;
constexpr float OML      = 1.0f - LAM_INIT;          // (1 - lambda_init)
constexpr float QKSCALE  = 0.08838834764831845f;     // 128^-0.5
constexpr float RESCALE_THR = 8.0f;

__device__ __forceinline__ unsigned short f2bf(float f) {
  unsigned int u = __builtin_bit_cast(unsigned int, f);
  u += 0x7fffu + ((u >> 16) & 1u);   // RNE
  return (unsigned short)(u >> 16);
}

__device__ __forceinline__ unsigned int cvtpk(float lo, float hi) {
  unsigned int r;
  asm("v_cvt_pk_bf16_f32 %0, %1, %2" : "=v"(r) : "v"(lo), "v"(hi));
  return r;
}

__device__ __forceinline__ void g2l16(const void* gsrc, void* ldst) {
  __builtin_amdgcn_global_load_lds(
      (const __attribute__((address_space(1))) unsigned int*)gsrc,
      (__attribute__((address_space(3))) unsigned int*)ldst, 16, 0, 0);
}

// fp32 -> bf16 bulk convert, single tensor (out_w), 2048 elems/block
__global__ __launch_bounds__(256)
void cvt1(const float* __restrict__ s, unsigned short* __restrict__ d)
{
  const int i = (blockIdx.x << 11) + (int)threadIdx.x * 8;
  const float4 a0 = *(const float4*)(s + i);
  const float4 a1 = *(const float4*)(s + i + 4);
  u16x8 v;
  v[0]=f2bf(a0.x); v[1]=f2bf(a0.y); v[2]=f2bf(a0.z); v[3]=f2bf(a0.w);
  v[4]=f2bf(a1.x); v[5]=f2bf(a1.y); v[6]=f2bf(a1.z); v[7]=f2bf(a1.w);
  *(u16x8*)(d + i) = v;
}

// out = p[0] + p[1] + bias  (split-K reduce, fp32, float4)
__global__ __launch_bounds__(256)
void reduce2(const float* __restrict__ p, const float* __restrict__ bias,
             float* __restrict__ out)
{
  const size_t i = ((size_t)blockIdx.x * 256 + threadIdx.x) * 4;
  const int col = (int)(i & (HIDN - 1));
  const float4 a = *(const float4*)(p + i);
  const float4 b = *(const float4*)(p + (size_t)TTOK * HIDN + i);
  const float4 c = *(const float4*)(bias + col);
  float4 r;
  r.x = a.x + b.x + c.x; r.y = a.y + b.y + c.y;
  r.z = a.z + b.z + c.z; r.w = a.w + b.w + c.w;
  *(float4*)(out + i) = r;
}

// GEMM1: qkv = hs @ wqkv_w^T + bias, FP32 INPUTS, fused convert in staging.
// BM=256 x BN=192 x BK=64, grid (32,8)=256 blocks, 8 waves 4M x 2N.
// Staging: 14 global_load_dwordx4 (fp32, coalesced) issued TWO tiles ahead;
// converted via v_cvt_pk_bf16_f32 + ds_write_b128 to SWIZZLED LDS dest
// (write-side swizzle col8^(row&7) == read-side ck^rsw involution).
// One lgkmcnt(0)+barrier per K-tile; no manual vmcnt (reg loads are
// compiler-tracked).  B frags register-held across A-halves.
// Epilogue per 16-col region group; Q pre-scaled by QKSCALE.
__global__ __launch_bounds__(512, 2)
void gemm1_qkv(const float* __restrict__ A, const float* __restrict__ B,
               const float* __restrict__ bias, unsigned short* __restrict__ qq,
               unsigned short* __restrict__ ctt)
{
  __shared__ __align__(16) unsigned short As[2][2][128 * 64];
  __shared__ __align__(16) unsigned short Bs[2][192 * 64];

  const int tid  = threadIdx.x;
  const int lane = tid & 63, wid = tid >> 6;
  const int wm = wid >> 1, wn = wid & 1;            // 4 M x 2 N wave grid
  const int m0 = blockIdx.y * 256, n0 = blockIdx.x * 192;
  const int l15 = lane & 15, lg = lane >> 4;

  // staging thread mapping: row = i*64 + (tid>>3), col8 = tid&7 (8 fp32 elems)
  const int srow = tid >> 3;
  const int sc8  = (tid & 7) << 3;                        // elem col of loads
  const int swc  = (((tid & 7) ^ (srow & 7))) << 3;       // swizzled LDS col
  // fragment reads: swizzled col constants (row&7 == l15&7 for all frags)
  const int rsw = (l15 & 7) << 3;
  const int ck0 = (lg * 8) ^ rsw;
  const int ck1 = (32 + lg * 8) ^ rsw;
  const int arh = wm * 16 + l15;        // + ml*64 within A-half
  const int brh = wn * 96 + l15;        // + ni*16

  fx4 la[2][2][2];   // [half][iter][lo/hi] fp32 in-flight A
  fx4 lb[3][2];      // [iter][lo/hi]      fp32 in-flight B

  auto issueLoads = [&](int kt) {
    #pragma unroll
    for (int h = 0; h < 2; ++h)
      #pragma unroll
      for (int i = 0; i < 2; ++i) {
        const float* ap = A + (size_t)(m0 + h * 128 + i * 64 + srow) * HIDN + kt + sc8;
        la[h][i][0] = *(const fx4*)ap;
        la[h][i][1] = *(const fx4*)(ap + 4);
      }
    #pragma unroll
    for (int i = 0; i < 3; ++i) {
      const float* bp = B + (size_t)(n0 + i * 64 + srow) * HIDN + kt + sc8;
      lb[i][0] = *(const fx4*)bp;
      lb[i][1] = *(const fx4*)(bp + 4);
    }
  };
  auto writeStage = [&](int buf) {
    #pragma unroll
    for (int h = 0; h < 2; ++h)
      #pragma unroll
      for (int i = 0; i < 2; ++i) {
        uint4 w;
        w.x = cvtpk(la[h][i][0][0], la[h][i][0][1]);
        w.y = cvtpk(la[h][i][0][2], la[h][i][0][3]);
        w.z = cvtpk(la[h][i][1][0], la[h][i][1][1]);
        w.w = cvtpk(la[h][i][1][2], la[h][i][1][3]);
        *(uint4*)&As[buf][h][(i * 64 + srow) * 64 + swc] = w;
      }
    #pragma unroll
    for (int i = 0; i < 3; ++i) {
      uint4 w;
      w.x = cvtpk(lb[i][0][0], lb[i][0][1]);
      w.y = cvtpk(lb[i][0][2], lb[i][0][3]);
      w.z = cvtpk(lb[i][1][0], lb[i][1][1]);
      w.w = cvtpk(lb[i][1][2], lb[i][1][3]);
      *(uint4*)&Bs[buf][(i * 64 + srow) * 64 + swc] = w;
    }
  };

  fx4 acc[4][6] = {};

  const int nk = HIDN >> 6;             // 64 K-tiles
  issueLoads(0);
  writeStage(0);
  issueLoads(64);
  asm volatile("s_waitcnt lgkmcnt(0)" ::: "memory");
  __builtin_amdgcn_s_barrier();

  for (int t = 0; t < nk; ++t) {
    const int buf = t & 1, nb = buf ^ 1;
    const unsigned short* A0 = &As[buf][0][0];
    const unsigned short* A1 = &As[buf][1][0];
    const unsigned short* Bp = &Bs[buf][0];
    s16x8 af[2], bk0[6], bk1[6];

    // ---- q0: (A-half0, k0) ----
    af[0] = *(const s16x8*)&A0[(arh)      * 64 + ck0];
    af[1] = *(const s16x8*)&A0[(arh + 64) * 64 + ck0];
    #pragma unroll
    for (int n = 0; n < 6; ++n)
      bk0[n] = *(const s16x8*)&Bp[(brh + n * 16) * 64 + ck0];
    __builtin_amdgcn_s_setprio(1);
    #pragma unroll
    for (int m = 0; m < 2; ++m)
      #pragma unroll
      for (int n = 0; n < 6; ++n)
        acc[m][n] = __builtin_amdgcn_mfma_f32_16x16x32_bf16(af[m], bk0[n], acc[m][n], 0, 0, 0);
    __builtin_amdgcn_s_setprio(0);

    // ---- q1: (A-half0, k1) ----
    af[0] = *(const s16x8*)&A0[(arh)      * 64 + ck1];
    af[1] = *(const s16x8*)&A0[(arh + 64) * 64 + ck1];
    #pragma unroll
    for (int n = 0; n < 6; ++n)
      bk1[n] = *(const s16x8*)&Bp[(brh + n * 16) * 64 + ck1];
    __builtin_amdgcn_s_setprio(1);
    #pragma unroll
    for (int m = 0; m < 2; ++m)
      #pragma unroll
      for (int n = 0; n < 6; ++n)
        acc[m][n] = __builtin_amdgcn_mfma_f32_16x16x32_bf16(af[m], bk1[n], acc[m][n], 0, 0, 0);
    __builtin_amdgcn_s_setprio(0);

    // ---- q2: (A-half1, k0) with reg-held Bk0; convert+write next tile;
    //          issue loads for tile t+2 (4-phase issue->use distance) ----
    af[0] = *(const s16x8*)&A1[(arh)      * 64 + ck0];
    af[1] = *(const s16x8*)&A1[(arh + 64) * 64 + ck0];
    if (t + 1 < nk) writeStage(nb);
    if (t + 2 < nk) issueLoads((t + 2) << 6);
    __builtin_amdgcn_s_setprio(1);
    #pragma unroll
    for (int m = 0; m < 2; ++m)
      #pragma unroll
      for (int n = 0; n < 6; ++n)
        acc[2 + m][n] = __builtin_amdgcn_mfma_f32_16x16x32_bf16(af[m], bk0[n], acc[2 + m][n], 0, 0, 0);
    __builtin_amdgcn_s_setprio(0);

    // ---- q3: (A-half1, k1) with reg-held Bk1 ----
    af[0] = *(const s16x8*)&A1[(arh)      * 64 + ck1];
    af[1] = *(const s16x8*)&A1[(arh + 64) * 64 + ck1];
    __builtin_amdgcn_s_setprio(1);
    #pragma unroll
    for (int m = 0; m < 2; ++m)
      #pragma unroll
      for (int n = 0; n < 6; ++n)
        acc[2 + m][n] = __builtin_amdgcn_mfma_f32_16x16x32_bf16(af[m], bk1[n], acc[2 + m][n], 0, 0, 0);
    __builtin_amdgcn_s_setprio(0);

    if (t + 1 < nk) {
      asm volatile("s_waitcnt lgkmcnt(0)" ::: "memory");   // drain ds_writes (publish nb)
      __builtin_amdgcn_s_barrier();
    }
  }

  // epilogue: row = m0 + mi*64 + wm*16 + lg*4 + jj ; col = n0 + wn*96 + ni*16 + l15
  #pragma unroll
  for (int mi = 0; mi < 4; ++mi)
    #pragma unroll
    for (int ni = 0; ni < 6; ++ni) {
      const int colg = n0 + wn * 96 + ni * 16;      // 16-col group, region-uniform
      const int col  = colg + l15;
      const float bv = bias[col];
      const fx4 a = acc[mi][ni];
      const int row0 = m0 + mi * 64 + wm * 16 + lg * 4;
      if (colg >= VOFF) {
        ushort4 pk;
        pk.x = f2bf(a[0] + bv); pk.y = f2bf(a[1] + bv);
        pk.z = f2bf(a[2] + bv); pk.w = f2bf(a[3] + bv);
        const int d = col - VOFF;
        const int kvp = d >> 8, dw = d & 255;
        const int kt2 = row0 >> 5, kk = row0 & 31;
        const int kc = kk >> 3, k8 = kk & 7;
        *(ushort4*)&ctt[(size_t)kvp * 1048576 + (size_t)kt2 * 16384 + 8192
                        + kc * 2048 + dw * 8 + k8] = pk;
      } else if (colg >= KOFF) {
        const int ccol = col - KOFF;
        const int kvp = ccol >> 8, cw = ccol & 255;
        const int cc = cw >> 3, cbt = cw & 7;
        #pragma unroll
        for (int jj = 0; jj < 4; ++jj) {
          const int row2 = row0 + jj;
          const int kt2 = row2 >> 5, kk = row2 & 31;
          ctt[(size_t)kvp * 1048576 + (size_t)kt2 * 16384 + cc * 256 + kk * 8 + cbt]
              = f2bf(a[jj] + bv);
        }
      } else {
        #pragma unroll
        for (int jj = 0; jj < 4; ++jj)
          qq[(size_t)(row0 + jj) * HIDN + col] = f2bf((a[jj] + bv) * QKSCALE);
      }
    }
}

// GEMM2 split-K partial (fp32): 8 waves 2M x 4N interleaved, 256x256xBK64,
// 4 phases with counted vmcnt(4), B0 register-held, 3 barriers/K-tile.
__global__ __launch_bounds__(512, 2)
void gemm2_sk(const unsigned short* __restrict__ A, const unsigned short* __restrict__ B,
              float* __restrict__ P, int K, int lda, int ldb, int ldc)
{
  __shared__ __align__(16) unsigned short As[2][2][128 * 64];
  __shared__ __align__(16) unsigned short Bs[2][2][128 * 64];

  const int tid  = threadIdx.x;
  const int lane = tid & 63, wid = tid >> 6;
  const int wm = wid >> 2, wn = wid & 3;
  const int m0 = blockIdx.y * 256, n0 = blockIdx.x * 256;
  const int l15 = lane & 15, lg = lane >> 4;
  const int kOff = blockIdx.z * K;

  const int scol = ((tid & 7) ^ ((tid >> 3) & 7)) << 3;
  const int rsw = (l15 & 7) << 3;
  const int ck0 = (lg * 8) ^ rsw;
  const int ck1 = (32 + lg * 8) ^ rsw;
  const int arh = wm * 16 + l15;
  const int brh = wn * 16 + l15;

  auto stageAh = [&](int kt, int buf, int h) {
    #pragma unroll
    for (int i = 0; i < 2; ++i) {
      const int li = i * 512 + tid;
      g2l16(A + (size_t)(m0 + h * 128 + (li >> 3)) * lda + kOff + kt + scol,
            &As[buf][h][li * 8]);
    }
  };
  auto stageBh = [&](int kt, int buf, int h) {
    #pragma unroll
    for (int i = 0; i < 2; ++i) {
      const int li = i * 512 + tid;
      g2l16(B + (size_t)(n0 + h * 128 + (li >> 3)) * ldb + kOff + kt + scol,
            &Bs[buf][h][li * 8]);
    }
  };

  fx4 acc[8][4] = {};

  const int nk = K >> 6;
  stageAh(0, 0, 0); stageBh(0, 0, 0); stageBh(0, 0, 1); stageAh(0, 0, 1);
  asm volatile("s_waitcnt vmcnt(0)" ::: "memory");
  __builtin_amdgcn_s_barrier();

  for (int t = 0; t < nk; ++t) {
    const int buf = t & 1, nb = buf ^ 1;
    const int kt1 = (t + 1) << 6;
    const bool pre = (t + 1) < nk;
    const unsigned short* A0 = &As[buf][0][0];
    const unsigned short* A1 = &As[buf][1][0];
    const unsigned short* B0 = &Bs[buf][0][0];
    const unsigned short* B1 = &Bs[buf][1][0];
    s16x8 af[4][2], bf0[2][2], bf1[2][2];

    // q0: (A0,B0)
    #pragma unroll
    for (int m = 0; m < 4; ++m) {
      af[m][0] = *(const s16x8*)&A0[(arh + m * 32) * 64 + ck0];
      af[m][1] = *(const s16x8*)&A0[(arh + m * 32) * 64 + ck1];
    }
    #pragma unroll
    for (int n = 0; n < 2; ++n) {
      bf0[n][0] = *(const s16x8*)&B0[(brh + n * 64) * 64 + ck0];
      bf0[n][1] = *(const s16x8*)&B0[(brh + n * 64) * 64 + ck1];
    }
    if (pre) {
      stageAh(kt1, nb, 0);
      asm volatile("s_waitcnt vmcnt(4)" ::: "memory");
    } else {
      asm volatile("s_waitcnt vmcnt(0)" ::: "memory");
    }
    __builtin_amdgcn_s_barrier();
    __builtin_amdgcn_s_setprio(1);
    #pragma unroll
    for (int m = 0; m < 4; ++m)
      #pragma unroll
      for (int n = 0; n < 2; ++n) {
        acc[m][n] = __builtin_amdgcn_mfma_f32_16x16x32_bf16(af[m][0], bf0[n][0], acc[m][n], 0, 0, 0);
        acc[m][n] = __builtin_amdgcn_mfma_f32_16x16x32_bf16(af[m][1], bf0[n][1], acc[m][n], 0, 0, 0);
      }
    __builtin_amdgcn_s_setprio(0);

    // q1: (A0,B1)
    #pragma unroll
    for (int n = 0; n < 2; ++n) {
      bf1[n][0] = *(const s16x8*)&B1[(brh + n * 64) * 64 + ck0];
      bf1[n][1] = *(const s16x8*)&B1[(brh + n * 64) * 64 + ck1];
    }
    if (pre) {
      stageBh(kt1, nb, 0);
      asm volatile("s_waitcnt vmcnt(4)" ::: "memory");
    }
    __builtin_amdgcn_s_barrier();
    __builtin_amdgcn_s_setprio(1);
    #pragma unroll
    for (int m = 0; m < 4; ++m)
      #pragma unroll
      for (int n = 0; n < 2; ++n) {
        acc[m][2 + n] = __builtin_amdgcn_mfma_f32_16x16x32_bf16(af[m][0], bf1[n][0], acc[m][2 + n], 0, 0, 0);
        acc[m][2 + n] = __builtin_amdgcn_mfma_f32_16x16x32_bf16(af[m][1], bf1[n][1], acc[m][2 + n], 0, 0, 0);
      }
    __builtin_amdgcn_s_setprio(0);

    // q2: (A1,B1)
    #pragma unroll
    for (int m = 0; m < 4; ++m) {
      af[m][0] = *(const s16x8*)&A1[(arh + m * 32) * 64 + ck0];
      af[m][1] = *(const s16x8*)&A1[(arh + m * 32) * 64 + ck1];
    }
    if (pre) stageBh(kt1, nb, 1);
    __builtin_amdgcn_s_setprio(1);
    #pragma unroll
    for (int m = 0; m < 4; ++m)
      #pragma unroll
      for (int n = 0; n < 2; ++n) {
        acc[4 + m][2 + n] = __builtin_amdgcn_mfma_f32_16x16x32_bf16(af[m][0], bf1[n][0], acc[4 + m][2 + n], 0, 0, 0);
        acc[4 + m][2 + n] = __builtin_amdgcn_mfma_f32_16x16x32_bf16(af[m][1], bf1[n][1], acc[4 + m][2 + n], 0, 0, 0);
      }
    __builtin_amdgcn_s_setprio(0);

    // q3: (A1,B0) from registers; MFMA first, then wait
    if (pre) stageAh(kt1, nb, 1);
    __builtin_amdgcn_s_setprio(1);
    #pragma unroll
    for (int m = 0; m < 4; ++m)
      #pragma unroll
      for (int n = 0; n < 2; ++n) {
        acc[4 + m][n] = __builtin_amdgcn_mfma_f32_16x16x32_bf16(af[m][0], bf0[n][0], acc[4 + m][n], 0, 0, 0);
        acc[4 + m][n] = __builtin_amdgcn_mfma_f32_16x16x32_bf16(af[m][1], bf0[n][1], acc[4 + m][n], 0, 0, 0);
      }
    __builtin_amdgcn_s_setprio(0);
    if (pre) asm volatile("s_waitcnt vmcnt(4)" ::: "memory");
    __builtin_amdgcn_s_barrier();
  }

  float* Pz = P + (size_t)blockIdx.z * TTOK * ldc;
  const int rb = m0 + wm * 16;
  const int cb = n0 + wn * 16;
  #pragma unroll
  for (int mi = 0; mi < 8; ++mi)
    #pragma unroll
    for (int ni = 0; ni < 4; ++ni) {
      const int col = cb + ni * 64 + l15;
      const fx4 a = acc[mi][ni];
      #pragma unroll
      for (int jj = 0; jj < 4; ++jj)
        Pz[(size_t)(rb + mi * 32 + lg * 4 + jj) * ldc + col] = a[jj];
    }
}

// Block = (pair, 64 q-rows), 4 waves (16 rows each, both diff components).
// Complementary balanced decode; K/V staged per 32-key tile via
// global_load_lds from tile-contiguous ctt, double-buffered, one barrier/tile.
// P pack uses v_cvt_pk_bf16_f32 (1 op / 2 values, HW RNE).
__global__ __launch_bounds__(256, 2)
void attn_kernel(const unsigned short* __restrict__ qq,    // [TTOK][HIDN] bf16 Q*scale
                 const unsigned short* __restrict__ ctt,   // tiled K/V
                 const float* __restrict__ lq1, const float* __restrict__ lk1,
                 const float* __restrict__ lq2, const float* __restrict__ lk2,
                 const float* __restrict__ subln,
                 unsigned short* __restrict__ attn_out)    // [TTOK][HIDN] bf16
{
  __shared__ __align__(16) unsigned short Sb[2][16384];    // [K 16KB][V 16KB]
  __shared__ __align__(16) unsigned short Pl[4][2][640];
  const int tid = threadIdx.x;
  const int lane = tid & 63, w = tid >> 6;
  const int l15 = lane & 15, lg = lane >> 4;

  // balanced decode
  const int bid  = blockIdx.x;
  const int r    = bid & 255;
  const int pair = r & 15;
  const int x    = r >> 4;                    // 0..15
  const int qb   = (bid >> 8) ? x : 31 - x;   // heavy half first
  const int kvp  = pair >> 2;
  const int q0b  = qb * 64;
  const int q0w  = q0b + w * 16;
  const int nt   = 2 * qb + 2;

  const unsigned short* cbase = ctt + (size_t)kvp * 1048576;

  auto stage = [&](int kt, int buf) {
    const unsigned short* src = cbase + (size_t)kt * 16384;
    const int off = w * 512 + lane * 8;
    #pragma unroll
    for (int i = 0; i < 8; ++i) {
      const int o = i * 2048 + off;
      g2l16(src + o, &Sb[buf][o]);
    }
  };

  stage(0, 0);

  // lambda via wave-parallel dot
  float a1 = lq1[lane] * lk1[lane] + lq1[lane + 64] * lk1[lane + 64];
  float a2 = lq2[lane] * lk2[lane] + lq2[lane + 64] * lk2[lane + 64];
  #pragma unroll
  for (int sft = 1; sft < 64; sft <<= 1) { a1 += __shfl_xor(a1, sft); a2 += __shfl_xor(a2, sft); }
  const float lam = __expf(a1) - __expf(a2) + LAM_INIT;

  // Q fragments (pre-scaled)
  s16x8 qf0[4], qf1[4];
  {
    const unsigned short* qbp = qq + (size_t)(q0w + l15) * HIDN + pair * VD + lg * 8;
    #pragma unroll
    for (int kf = 0; kf < 4; ++kf) {
      qf0[kf] = *(const s16x8*)(qbp + kf * 32);
      qf1[kf] = *(const s16x8*)(qbp + DH + kf * 32);
    }
  }

  float mrun0 = -1e30f, mrun1 = -1e30f;
  float lrun0 = 0.f, lrun1 = 0.f;
  fx4 oacc0[16] = {}, oacc1[16] = {};
  unsigned short* pl0 = &Pl[w][0][0];
  unsigned short* pl1 = &Pl[w][1][0];
  const int q = q0w + l15;
  const int qmax = q0w + 15;

  for (int t = 0; t < nt; ++t) {
    __syncthreads();                      // stage(t) visible; buf[(t+1)&1] free
    if (t + 1 < nt) stage(t + 1, (t + 1) & 1);
    const int kb = t * 32;
    if (kb > qmax) continue;              // wave-uniform; still hits barrier next iter
    const unsigned short* Kl = Sb[t & 1];
    const unsigned short* Vl = Sb[t & 1] + 8192;

    // ---- QK^T swapped: S^T[key][q]
    fx4 s00 = {0,0,0,0}, s01 = {0,0,0,0}, s10 = {0,0,0,0}, s11 = {0,0,0,0};
    #pragma unroll
    for (int kf = 0; kf < 4; ++kf) {
      const int cc0 = kf * 4 + lg;
      const int cc1 = 16 + kf * 4 + lg;
      const s16x8 k00 = *(const s16x8*)&Kl[cc0 * 256 + l15 * 8];
      const s16x8 k01 = *(const s16x8*)&Kl[cc0 * 256 + (16 + l15) * 8];
      const s16x8 k10 = *(const s16x8*)&Kl[cc1 * 256 + l15 * 8];
      const s16x8 k11 = *(const s16x8*)&Kl[cc1 * 256 + (16 + l15) * 8];
      s00 = __builtin_amdgcn_mfma_f32_16x16x32_bf16(k00, qf0[kf], s00, 0, 0, 0);
      s01 = __builtin_amdgcn_mfma_f32_16x16x32_bf16(k01, qf0[kf], s01, 0, 0, 0);
      s10 = __builtin_amdgcn_mfma_f32_16x16x32_bf16(k10, qf1[kf], s10, 0, 0, 0);
      s11 = __builtin_amdgcn_mfma_f32_16x16x32_bf16(k11, qf1[kf], s11, 0, 0, 0);
    }

    // ---- mask (full-tile fast path)
    float v0[8], v1[8];
    if (kb + 32 <= q0w) {
      #pragma unroll
      for (int j = 0; j < 4; ++j) {
        v0[j] = s00[j]; v0[4 + j] = s01[j];
        v1[j] = s10[j]; v1[4 + j] = s11[j];
      }
    } else {
      #pragma unroll
      for (int j = 0; j < 4; ++j) {
        const int klo = kb + lg * 4 + j, khi = klo + 16;
        v0[j]     = (klo <= q) ? s00[j] : -1e30f;
        v0[4 + j] = (khi <= q) ? s01[j] : -1e30f;
        v1[j]     = (klo <= q) ? s10[j] : -1e30f;
        v1[4 + j] = (khi <= q) ? s11[j] : -1e30f;
      }
    }
    // ---- tile max per comp
    float tm0 = fmaxf(fmaxf(fmaxf(v0[0],v0[1]),fmaxf(v0[2],v0[3])),
                      fmaxf(fmaxf(v0[4],v0[5]),fmaxf(v0[6],v0[7])));
    float tm1 = fmaxf(fmaxf(fmaxf(v1[0],v1[1]),fmaxf(v1[2],v1[3])),
                      fmaxf(fmaxf(v1[4],v1[5]),fmaxf(v1[6],v1[7])));
    tm0 = fmaxf(tm0, __shfl_xor(tm0, 16)); tm0 = fmaxf(tm0, __shfl_xor(tm0, 32));
    tm1 = fmaxf(tm1, __shfl_xor(tm1, 16)); tm1 = fmaxf(tm1, __shfl_xor(tm1, 32));

    // ---- defer-max rescale (rare)
    const bool need = (tm0 > mrun0 + RESCALE_THR) || (tm1 > mrun1 + RESCALE_THR);
    if (__any(need)) {
      const float mn0 = fmaxf(mrun0, tm0), mn1 = fmaxf(mrun1, tm1);
      const float fac0 = __expf(mrun0 - mn0), fac1 = __expf(mrun1 - mn1);
      mrun0 = mn0; mrun1 = mn1;
      lrun0 *= fac0; lrun1 *= fac1;
      #pragma unroll
      for (int jj = 0; jj < 4; ++jj) {
        const float fr0 = __shfl(fac0, lg * 4 + jj);
        const float fr1 = __shfl(fac1, lg * 4 + jj);
        #pragma unroll
        for (int nf = 0; nf < 16; ++nf) { oacc0[nf][jj] *= fr0; oacc1[nf][jj] *= fr1; }
      }
    }

    // ---- P = exp(v - mrun); pack via v_cvt_pk_bf16_f32 -> per-wave LDS transpose
    {
      float e0[8], e1[8];
      #pragma unroll
      for (int j = 0; j < 8; ++j) {
        e0[j] = __expf(v0[j] - mrun0);
        e1[j] = __expf(v1[j] - mrun1);
      }
      lrun0 += ((e0[0]+e0[1])+(e0[2]+e0[3])) + ((e0[4]+e0[5])+(e0[6]+e0[7]));
      lrun1 += ((e1[0]+e1[1])+(e1[2]+e1[3])) + ((e1[4]+e1[5])+(e1[6]+e1[7]));
      uint2 lo0, hi0, lo1, hi1;
      lo0.x = cvtpk(e0[0], e0[1]); lo0.y = cvtpk(e0[2], e0[3]);
      hi0.x = cvtpk(e0[4], e0[5]); hi0.y = cvtpk(e0[6], e0[7]);
      lo1.x = cvtpk(e1[0], e1[1]); lo1.y = cvtpk(e1[2], e1[3]);
      hi1.x = cvtpk(e1[4], e1[5]); hi1.y = cvtpk(e1[6], e1[7]);
      *(uint2*)&pl0[l15 * 40 + lg * 4]      = lo0;
      *(uint2*)&pl0[l15 * 40 + 16 + lg * 4] = hi0;
      *(uint2*)&pl1[l15 * 40 + lg * 4]      = lo1;
      *(uint2*)&pl1[l15 * 40 + 16 + lg * 4] = hi1;
    }
    asm volatile("s_waitcnt lgkmcnt(0)" ::: "memory");
    __builtin_amdgcn_sched_barrier(0);

    // ---- PV from LDS V tile (conflict-free layout)
    const s16x8 pa0 = *(const s16x8*)&pl0[l15 * 40 + lg * 8];
    const s16x8 pa1 = *(const s16x8*)&pl1[l15 * 40 + lg * 8];
    #pragma unroll
    for (int nf = 0; nf < 16; ++nf) {
      const s16x8 vf = *(const s16x8*)&Vl[lg * 2048 + (nf * 16 + l15) * 8];
      oacc0[nf] = __builtin_amdgcn_mfma_f32_16x16x32_bf16(pa0, vf, oacc0[nf], 0, 0, 0);
      oacc1[nf] = __builtin_amdgcn_mfma_f32_16x16x32_bf16(pa1, vf, oacc1[nf], 0, 0, 0);
    }
  }

  // ---- finalize row sums
  lrun0 += __shfl_xor(lrun0, 16); lrun0 += __shfl_xor(lrun0, 32);
  lrun1 += __shfl_xor(lrun1, 16); lrun1 += __shfl_xor(lrun1, 32);

  float li0[4], li1[4];
  #pragma unroll
  for (int jj = 0; jj < 4; ++jj) {
    li0[jj] = 1.0f / __shfl(lrun0, lg * 4 + jj);
    li1[jj] = 1.0f / __shfl(lrun1, lg * 4 + jj);
  }

  // ---- combine, RMSNorm over 256, scale, store
  float ss[4] = {0.f, 0.f, 0.f, 0.f};
  #pragma unroll
  for (int nf = 0; nf < 16; ++nf)
    #pragma unroll
    for (int jj = 0; jj < 4; ++jj) {
      const float o = oacc0[nf][jj] * li0[jj] - lam * oacc1[nf][jj] * li1[jj];
      oacc0[nf][jj] = o;
      ss[jj] += o * o;
    }
  #pragma unroll
  for (int jj = 0; jj < 4; ++jj) {
    ss[jj] += __shfl_xor(ss[jj], 1);
    ss[jj] += __shfl_xor(ss[jj], 2);
    ss[jj] += __shfl_xor(ss[jj], 4);
    ss[jj] += __shfl_xor(ss[jj], 8);
    ss[jj] = rsqrtf(ss[jj] * (1.0f / 256.0f) + 1e-5f) * OML;
  }
  #pragma unroll
  for (int nf = 0; nf < 16; ++nf) {
    const int dcol = nf * 16 + l15;
    const float sw = subln[dcol];
    #pragma unroll
    for (int jj = 0; jj < 4; ++jj) {
      const int t = q0w + lg * 4 + jj;
      attn_out[(size_t)t * HIDN + pair * VD + dcol] = f2bf(oacc0[nf][jj] * ss[jj] * sw);
    }
  }
}

extern "C" void kernel_launch(void* const* d_in, const int* in_sizes, int n_in,
                              void* d_out, int out_size, void* d_ws, size_t ws_size,
                              hipStream_t stream) {
  (void)in_sizes; (void)n_in; (void)out_size; (void)ws_size;
  const float* hs     = (const float*)d_in[0];
  const float* wqkv_w = (const float*)d_in[1];
  const float* wqkv_b = (const float*)d_in[2];
  const float* lq1    = (const float*)d_in[3];
  const float* lk1    = (const float*)d_in[4];
  const float* lq2    = (const float*)d_in[5];
  const float* lk2    = (const float*)d_in[6];
  const float* subln  = (const float*)d_in[7];
  const float* out_w  = (const float*)d_in[8];
  const float* out_b  = (const float*)d_in[9];

  unsigned short* qq       = (unsigned short*)d_ws;
  unsigned short* ctt      = qq + (size_t)TTOK * HIDN;
  unsigned short* attn_out = ctt + (size_t)4 * 1048576;
  unsigned short* scratch  = attn_out + (size_t)TTOK * HIDN;
  unsigned short* outw_bf  = scratch + (size_t)2 * TTOK * HIDN * 2;  // after partial space
  float*          partial  = (float*)scratch;   // 2 x [2048][4096] fp32

  // convert only out_w (hs/wqkv conversion fused into gemm1)
  cvt1<<<dim3((HIDN * HIDN) >> 11), 256, 0, stream>>>(out_w, outw_bf);

  // GEMM1: fp32 inputs, fused convert; 256x192 tiles -> grid (32,8) = 256 blocks
  gemm1_qkv<<<dim3(OPD / 192, TTOK / 256), 512, 0, stream>>>(
      hs, wqkv_w, wqkv_b, qq, ctt);

  // Attention + combine + RMSNorm -> attn_out (bf16)
  attn_kernel<<<dim3(512), 256, 0, stream>>>(
      qq, ctt, lq1, lk1, lq2, lk2, subln, attn_out);

  // GEMM2 split-K: 256 blocks (16 x 8 x 2), each K=2048 -> fp32 partials
  gemm2_sk<<<dim3(HIDN / 256, TTOK / 256, 2), 512, 0, stream>>>(
      attn_out, outw_bf, partial, HIDN / 2, HIDN, HIDN, HIDN);

  // out = partial0 + partial1 + out_b
  reduce2<<<dim3((TTOK * HIDN) / 1024), 256, 0, stream>>>(
      partial, out_b, (float*)d_out);
}

// Round 19
// 325.052 us; speedup vs baseline: 1.0525x; 1.0525x over previous
//
#include <hip/hip_runtime.h>

#define TTOK 2048
#define HIDN 4096
#define OPD  6144
#define DH   128
#define VD   256
#define KOFF 4096
#define VOFF 5120

typedef short  s16x8 __attribute__((ext_vector_type(8)));
typedef unsigned short u16x8 __attribute__((ext_vector_type(8)));
typedef float  fx4   __attribute__((ext_vector_type(4)));

constexpr float LAM_INIT = 0.7455692280263534f;
constexpr float OML      = 1.0f - LAM_INIT;          // (1 - lambda_init)
constexpr float QKSCALE  = 0.08838834764831845f;     // 128^-0.5
constexpr float RESCALE_THR = 8.0f;

__device__ __forceinline__ unsigned short f2bf(float f) {
  unsigned int u = __builtin_bit_cast(unsigned int, f);
  u += 0x7fffu + ((u >> 16) & 1u);   // RNE
  return (unsigned short)(u >> 16);
}

__device__ __forceinline__ unsigned int cvtpk(float lo, float hi) {
  unsigned int r;
  asm("v_cvt_pk_bf16_f32 %0, %1, %2" : "=v"(r) : "v"(lo), "v"(hi));
  return r;
}

__device__ __forceinline__ void g2l16(const void* gsrc, void* ldst) {
  __builtin_amdgcn_global_load_lds(
      (const __attribute__((address_space(1))) unsigned int*)gsrc,
      (__attribute__((address_space(3))) unsigned int*)ldst, 16, 0, 0);
}

// fp32 -> bf16 bulk convert, 3 tensors, 2048 elems/block (all sizes % 2048 == 0)
__global__ __launch_bounds__(256)
void cvt3(const float* __restrict__ s0, unsigned short* __restrict__ d0, int nb0,
          const float* __restrict__ s1, unsigned short* __restrict__ d1, int nb1,
          const float* __restrict__ s2, unsigned short* __restrict__ d2)
{
  const int b = blockIdx.x;
  const float* s; unsigned short* d; int base;
  if (b < nb0)            { s = s0; d = d0; base = b << 11; }
  else if (b < nb0 + nb1) { s = s1; d = d1; base = (b - nb0) << 11; }
  else                    { s = s2; d = d2; base = (b - nb0 - nb1) << 11; }
  const int i = base + (int)threadIdx.x * 8;
  const float4 a0 = *(const float4*)(s + i);
  const float4 a1 = *(const float4*)(s + i + 4);
  u16x8 v;
  v[0]=f2bf(a0.x); v[1]=f2bf(a0.y); v[2]=f2bf(a0.z); v[3]=f2bf(a0.w);
  v[4]=f2bf(a1.x); v[5]=f2bf(a1.y); v[6]=f2bf(a1.z); v[7]=f2bf(a1.w);
  *(u16x8*)(d + i) = v;
}

// out = p[0] + p[1] + bias  (split-K reduce, fp32, float4)
__global__ __launch_bounds__(256)
void reduce2(const float* __restrict__ p, const float* __restrict__ bias,
             float* __restrict__ out)
{
  const size_t i = ((size_t)blockIdx.x * 256 + threadIdx.x) * 4;
  const int col = (int)(i & (HIDN - 1));
  const float4 a = *(const float4*)(p + i);
  const float4 b = *(const float4*)(p + (size_t)TTOK * HIDN + i);
  const float4 c = *(const float4*)(bias + col);
  float4 r;
  r.x = a.x + b.x + c.x; r.y = a.y + b.y + c.y;
  r.z = a.z + b.z + c.z; r.w = a.w + b.w + c.w;
  *(float4*)(out + i) = r;
}

// GEMM1: qkv = hs_bf @ wqkv_bf^T + bias.  BM=128 x BN=192 x BK=64 -> grid
// (32,16) = 512 blocks; LDS 80 KB -> TWO blocks/CU (cross-block overlap hides
// barrier/wait stalls; every prior big-tile config ran 1 block/CU).
// 4 waves (2M x 2N), wave-tile 64x96, acc[4][6].  Per K-tile: q0 {vmcnt(0)
// (loads are 0.5-1 tile old), barrier, stage A(t+1), read kk0 frags, 24 MFMA}
// q1 {read kk1 frags, stage B(t+1), 24 MFMA}.  One wait + one barrier per
// tile, formally race-free ordering.  LDS XOR-swizzle.  Epilogue per 16-col
// region group; Q pre-scaled by QKSCALE.
__global__ __launch_bounds__(256, 2)
void gemm1_qkv(const unsigned short* __restrict__ A, const unsigned short* __restrict__ B,
               const float* __restrict__ bias, unsigned short* __restrict__ qq,
               unsigned short* __restrict__ ctt)
{
  __shared__ __align__(16) unsigned short As[2][128 * 64];   // 32 KB
  __shared__ __align__(16) unsigned short Bs[2][192 * 64];   // 48 KB

  const int tid  = threadIdx.x;
  const int lane = tid & 63, wid = tid >> 6;
  const int wm = wid >> 1, wn = wid & 1;            // 2 M x 2 N wave grid
  const int m0 = blockIdx.y * 128, n0 = blockIdx.x * 192;
  const int l15 = lane & 15, lg = lane >> 4;

  const int srow = tid >> 3;                                  // 0..31
  const int scol = ((tid & 7) ^ (srow & 7)) << 3;             // swizzled col
  const int rsw = (l15 & 7) << 3;
  const int ck0 = (lg * 8) ^ rsw;
  const int ck1 = (32 + lg * 8) ^ rsw;
  const int arh = wm * 64 + l15;        // + mi*16
  const int brh = wn * 96 + l15;        // + ni*16

  auto stageA = [&](int kt, int buf) {
    #pragma unroll
    for (int i = 0; i < 4; ++i) {
      const int li = i * 256 + tid;
      g2l16(A + (size_t)(m0 + (li >> 3)) * HIDN + kt + scol, &As[buf][li * 8]);
    }
  };
  auto stageB = [&](int kt, int buf) {
    #pragma unroll
    for (int i = 0; i < 6; ++i) {
      const int li = i * 256 + tid;
      g2l16(B + (size_t)(n0 + (li >> 3)) * HIDN + kt + scol, &Bs[buf][li * 8]);
    }
  };

  fx4 acc[4][6] = {};

  const int nk = HIDN >> 6;             // 64 K-tiles
  stageA(0, 0); stageB(0, 0);

  for (int t = 0; t < nk; ++t) {
    const int buf = t & 1, nb = buf ^ 1;
    const int kt1 = (t + 1) << 6;
    const bool pre = (t + 1) < nk;
    const unsigned short* Ap = &As[buf][0];
    const unsigned short* Bp = &Bs[buf][0];
    s16x8 af[4], bk[6];

    // ---- q0: drain tile t loads (issued >=0.5 tile ago), publish, stage A',
    //          read kk0 frags, 24 MFMA ----
    asm volatile("s_waitcnt vmcnt(0)" ::: "memory");
    __builtin_amdgcn_s_barrier();
    if (pre) stageA(kt1, nb);           // WAR: As[nb] last read before this barrier
    #pragma unroll
    for (int m = 0; m < 4; ++m)
      af[m] = *(const s16x8*)&Ap[(arh + m * 16) * 64 + ck0];
    #pragma unroll
    for (int n = 0; n < 6; ++n)
      bk[n] = *(const s16x8*)&Bp[(brh + n * 16) * 64 + ck0];
    __builtin_amdgcn_s_setprio(1);
    #pragma unroll
    for (int m = 0; m < 4; ++m)
      #pragma unroll
      for (int n = 0; n < 6; ++n)
        acc[m][n] = __builtin_amdgcn_mfma_f32_16x16x32_bf16(af[m], bk[n], acc[m][n], 0, 0, 0);
    __builtin_amdgcn_s_setprio(0);

    // ---- q1: read kk1 frags, stage B', 24 MFMA ----
    #pragma unroll
    for (int m = 0; m < 4; ++m)
      af[m] = *(const s16x8*)&Ap[(arh + m * 16) * 64 + ck1];
    #pragma unroll
    for (int n = 0; n < 6; ++n)
      bk[n] = *(const s16x8*)&Bp[(brh + n * 16) * 64 + ck1];
    if (pre) stageB(kt1, nb);           // WAR: Bs[nb] last read before q0 barrier
    __builtin_amdgcn_s_setprio(1);
    #pragma unroll
    for (int m = 0; m < 4; ++m)
      #pragma unroll
      for (int n = 0; n < 6; ++n)
        acc[m][n] = __builtin_amdgcn_mfma_f32_16x16x32_bf16(af[m], bk[n], acc[m][n], 0, 0, 0);
    __builtin_amdgcn_s_setprio(0);
  }

  // epilogue: row = m0 + wm*64 + mi*16 + lg*4 + jj ; col = n0 + wn*96 + ni*16 + l15
  #pragma unroll
  for (int mi = 0; mi < 4; ++mi)
    #pragma unroll
    for (int ni = 0; ni < 6; ++ni) {
      const int colg = n0 + wn * 96 + ni * 16;      // 16-col group, region-uniform
      const int col  = colg + l15;
      const float bv = bias[col];
      const fx4 a = acc[mi][ni];
      const int row0 = m0 + wm * 64 + mi * 16 + lg * 4;
      if (colg >= VOFF) {
        ushort4 pk;
        pk.x = f2bf(a[0] + bv); pk.y = f2bf(a[1] + bv);
        pk.z = f2bf(a[2] + bv); pk.w = f2bf(a[3] + bv);
        const int d = col - VOFF;
        const int kvp = d >> 8, dw = d & 255;
        const int kt2 = row0 >> 5, kk = row0 & 31;
        const int kc = kk >> 3, k8 = kk & 7;
        *(ushort4*)&ctt[(size_t)kvp * 1048576 + (size_t)kt2 * 16384 + 8192
                        + kc * 2048 + dw * 8 + k8] = pk;
      } else if (colg >= KOFF) {
        const int ccol = col - KOFF;
        const int kvp = ccol >> 8, cw = ccol & 255;
        const int cc = cw >> 3, cbt = cw & 7;
        #pragma unroll
        for (int jj = 0; jj < 4; ++jj) {
          const int row2 = row0 + jj;
          const int kt2 = row2 >> 5, kk = row2 & 31;
          ctt[(size_t)kvp * 1048576 + (size_t)kt2 * 16384 + cc * 256 + kk * 8 + cbt]
              = f2bf(a[jj] + bv);
        }
      } else {
        #pragma unroll
        for (int jj = 0; jj < 4; ++jj)
          qq[(size_t)(row0 + jj) * HIDN + col] = f2bf((a[jj] + bv) * QKSCALE);
      }
    }
}

// GEMM2 split-K partial (fp32): 8 waves 2M x 4N interleaved, 256x256xBK64,
// 4 phases with counted vmcnt(4), B0 register-held, 3 barriers/K-tile.
__global__ __launch_bounds__(512, 2)
void gemm2_sk(const unsigned short* __restrict__ A, const unsigned short* __restrict__ B,
              float* __restrict__ P, int K, int lda, int ldb, int ldc)
{
  __shared__ __align__(16) unsigned short As[2][2][128 * 64];
  __shared__ __align__(16) unsigned short Bs[2][2][128 * 64];

  const int tid  = threadIdx.x;
  const int lane = tid & 63, wid = tid >> 6;
  const int wm = wid >> 2, wn = wid & 3;
  const int m0 = blockIdx.y * 256, n0 = blockIdx.x * 256;
  const int l15 = lane & 15, lg = lane >> 4;
  const int kOff = blockIdx.z * K;

  const int scol = ((tid & 7) ^ ((tid >> 3) & 7)) << 3;
  const int rsw = (l15 & 7) << 3;
  const int ck0 = (lg * 8) ^ rsw;
  const int ck1 = (32 + lg * 8) ^ rsw;
  const int arh = wm * 16 + l15;
  const int brh = wn * 16 + l15;

  auto stageAh = [&](int kt, int buf, int h) {
    #pragma unroll
    for (int i = 0; i < 2; ++i) {
      const int li = i * 512 + tid;
      g2l16(A + (size_t)(m0 + h * 128 + (li >> 3)) * lda + kOff + kt + scol,
            &As[buf][h][li * 8]);
    }
  };
  auto stageBh = [&](int kt, int buf, int h) {
    #pragma unroll
    for (int i = 0; i < 2; ++i) {
      const int li = i * 512 + tid;
      g2l16(B + (size_t)(n0 + h * 128 + (li >> 3)) * ldb + kOff + kt + scol,
            &Bs[buf][h][li * 8]);
    }
  };

  fx4 acc[8][4] = {};

  const int nk = K >> 6;
  stageAh(0, 0, 0); stageBh(0, 0, 0); stageBh(0, 0, 1); stageAh(0, 0, 1);
  asm volatile("s_waitcnt vmcnt(0)" ::: "memory");
  __builtin_amdgcn_s_barrier();

  for (int t = 0; t < nk; ++t) {
    const int buf = t & 1, nb = buf ^ 1;
    const int kt1 = (t + 1) << 6;
    const bool pre = (t + 1) < nk;
    const unsigned short* A0 = &As[buf][0][0];
    const unsigned short* A1 = &As[buf][1][0];
    const unsigned short* B0 = &Bs[buf][0][0];
    const unsigned short* B1 = &Bs[buf][1][0];
    s16x8 af[4][2], bf0[2][2], bf1[2][2];

    // q0: (A0,B0)
    #pragma unroll
    for (int m = 0; m < 4; ++m) {
      af[m][0] = *(const s16x8*)&A0[(arh + m * 32) * 64 + ck0];
      af[m][1] = *(const s16x8*)&A0[(arh + m * 32) * 64 + ck1];
    }
    #pragma unroll
    for (int n = 0; n < 2; ++n) {
      bf0[n][0] = *(const s16x8*)&B0[(brh + n * 64) * 64 + ck0];
      bf0[n][1] = *(const s16x8*)&B0[(brh + n * 64) * 64 + ck1];
    }
    if (pre) {
      stageAh(kt1, nb, 0);
      asm volatile("s_waitcnt vmcnt(4)" ::: "memory");
    } else {
      asm volatile("s_waitcnt vmcnt(0)" ::: "memory");
    }
    __builtin_amdgcn_s_barrier();
    __builtin_amdgcn_s_setprio(1);
    #pragma unroll
    for (int m = 0; m < 4; ++m)
      #pragma unroll
      for (int n = 0; n < 2; ++n) {
        acc[m][n] = __builtin_amdgcn_mfma_f32_16x16x32_bf16(af[m][0], bf0[n][0], acc[m][n], 0, 0, 0);
        acc[m][n] = __builtin_amdgcn_mfma_f32_16x16x32_bf16(af[m][1], bf0[n][1], acc[m][n], 0, 0, 0);
      }
    __builtin_amdgcn_s_setprio(0);

    // q1: (A0,B1)
    #pragma unroll
    for (int n = 0; n < 2; ++n) {
      bf1[n][0] = *(const s16x8*)&B1[(brh + n * 64) * 64 + ck0];
      bf1[n][1] = *(const s16x8*)&B1[(brh + n * 64) * 64 + ck1];
    }
    if (pre) {
      stageBh(kt1, nb, 0);
      asm volatile("s_waitcnt vmcnt(4)" ::: "memory");
    }
    __builtin_amdgcn_s_barrier();
    __builtin_amdgcn_s_setprio(1);
    #pragma unroll
    for (int m = 0; m < 4; ++m)
      #pragma unroll
      for (int n = 0; n < 2; ++n) {
        acc[m][2 + n] = __builtin_amdgcn_mfma_f32_16x16x32_bf16(af[m][0], bf1[n][0], acc[m][2 + n], 0, 0, 0);
        acc[m][2 + n] = __builtin_amdgcn_mfma_f32_16x16x32_bf16(af[m][1], bf1[n][1], acc[m][2 + n], 0, 0, 0);
      }
    __builtin_amdgcn_s_setprio(0);

    // q2: (A1,B1)
    #pragma unroll
    for (int m = 0; m < 4; ++m) {
      af[m][0] = *(const s16x8*)&A1[(arh + m * 32) * 64 + ck0];
      af[m][1] = *(const s16x8*)&A1[(arh + m * 32) * 64 + ck1];
    }
    if (pre) stageBh(kt1, nb, 1);
    __builtin_amdgcn_s_setprio(1);
    #pragma unroll
    for (int m = 0; m < 4; ++m)
      #pragma unroll
      for (int n = 0; n < 2; ++n) {
        acc[4 + m][2 + n] = __builtin_amdgcn_mfma_f32_16x16x32_bf16(af[m][0], bf1[n][0], acc[4 + m][2 + n], 0, 0, 0);
        acc[4 + m][2 + n] = __builtin_amdgcn_mfma_f32_16x16x32_bf16(af[m][1], bf1[n][1], acc[4 + m][2 + n], 0, 0, 0);
      }
    __builtin_amdgcn_s_setprio(0);

    // q3: (A1,B0) from registers; MFMA first, then wait
    if (pre) stageAh(kt1, nb, 1);
    __builtin_amdgcn_s_setprio(1);
    #pragma unroll
    for (int m = 0; m < 4; ++m)
      #pragma unroll
      for (int n = 0; n < 2; ++n) {
        acc[4 + m][n] = __builtin_amdgcn_mfma_f32_16x16x32_bf16(af[m][0], bf0[n][0], acc[4 + m][n], 0, 0, 0);
        acc[4 + m][n] = __builtin_amdgcn_mfma_f32_16x16x32_bf16(af[m][1], bf0[n][1], acc[4 + m][n], 0, 0, 0);
      }
    __builtin_amdgcn_s_setprio(0);
    if (pre) asm volatile("s_waitcnt vmcnt(4)" ::: "memory");
    __builtin_amdgcn_s_barrier();
  }

  float* Pz = P + (size_t)blockIdx.z * TTOK * ldc;
  const int rb = m0 + wm * 16;
  const int cb = n0 + wn * 16;
  #pragma unroll
  for (int mi = 0; mi < 8; ++mi)
    #pragma unroll
    for (int ni = 0; ni < 4; ++ni) {
      const int col = cb + ni * 64 + l15;
      const fx4 a = acc[mi][ni];
      #pragma unroll
      for (int jj = 0; jj < 4; ++jj)
        Pz[(size_t)(rb + mi * 32 + lg * 4 + jj) * ldc + col] = a[jj];
    }
}

// Block = (pair, 64 q-rows), 4 waves (16 rows each, both diff components).
// Complementary balanced decode; K/V staged per 32-key tile via
// global_load_lds from tile-contiguous ctt, double-buffered, one barrier/tile.
// P pack uses v_cvt_pk_bf16_f32 (1 op / 2 values, HW RNE).
__global__ __launch_bounds__(256, 2)
void attn_kernel(const unsigned short* __restrict__ qq,    // [TTOK][HIDN] bf16 Q*scale
                 const unsigned short* __restrict__ ctt,   // tiled K/V
                 const float* __restrict__ lq1, const float* __restrict__ lk1,
                 const float* __restrict__ lq2, const float* __restrict__ lk2,
                 const float* __restrict__ subln,
                 unsigned short* __restrict__ attn_out)    // [TTOK][HIDN] bf16
{
  __shared__ __align__(16) unsigned short Sb[2][16384];    // [K 16KB][V 16KB]
  __shared__ __align__(16) unsigned short Pl[4][2][640];
  const int tid = threadIdx.x;
  const int lane = tid & 63, w = tid >> 6;
  const int l15 = lane & 15, lg = lane >> 4;

  // balanced decode
  const int bid  = blockIdx.x;
  const int r    = bid & 255;
  const int pair = r & 15;
  const int x    = r >> 4;                    // 0..15
  const int qb   = (bid >> 8) ? x : 31 - x;   // heavy half first
  const int kvp  = pair >> 2;
  const int q0b  = qb * 64;
  const int q0w  = q0b + w * 16;
  const int nt   = 2 * qb + 2;

  const unsigned short* cbase = ctt + (size_t)kvp * 1048576;

  auto stage = [&](int kt, int buf) {
    const unsigned short* src = cbase + (size_t)kt * 16384;
    const int off = w * 512 + lane * 8;
    #pragma unroll
    for (int i = 0; i < 8; ++i) {
      const int o = i * 2048 + off;
      g2l16(src + o, &Sb[buf][o]);
    }
  };

  stage(0, 0);

  // lambda via wave-parallel dot
  float a1 = lq1[lane] * lk1[lane] + lq1[lane + 64] * lk1[lane + 64];
  float a2 = lq2[lane] * lk2[lane] + lq2[lane + 64] * lk2[lane + 64];
  #pragma unroll
  for (int sft = 1; sft < 64; sft <<= 1) { a1 += __shfl_xor(a1, sft); a2 += __shfl_xor(a2, sft); }
  const float lam = __expf(a1) - __expf(a2) + LAM_INIT;

  // Q fragments (pre-scaled)
  s16x8 qf0[4], qf1[4];
  {
    const unsigned short* qbp = qq + (size_t)(q0w + l15) * HIDN + pair * VD + lg * 8;
    #pragma unroll
    for (int kf = 0; kf < 4; ++kf) {
      qf0[kf] = *(const s16x8*)(qbp + kf * 32);
      qf1[kf] = *(const s16x8*)(qbp + DH + kf * 32);
    }
  }

  float mrun0 = -1e30f, mrun1 = -1e30f;
  float lrun0 = 0.f, lrun1 = 0.f;
  fx4 oacc0[16] = {}, oacc1[16] = {};
  unsigned short* pl0 = &Pl[w][0][0];
  unsigned short* pl1 = &Pl[w][1][0];
  const int q = q0w + l15;
  const int qmax = q0w + 15;

  for (int t = 0; t < nt; ++t) {
    __syncthreads();                      // stage(t) visible; buf[(t+1)&1] free
    if (t + 1 < nt) stage(t + 1, (t + 1) & 1);
    const int kb = t * 32;
    if (kb > qmax) continue;              // wave-uniform; still hits barrier next iter
    const unsigned short* Kl = Sb[t & 1];
    const unsigned short* Vl = Sb[t & 1] + 8192;

    // ---- QK^T swapped: S^T[key][q]
    fx4 s00 = {0,0,0,0}, s01 = {0,0,0,0}, s10 = {0,0,0,0}, s11 = {0,0,0,0};
    #pragma unroll
    for (int kf = 0; kf < 4; ++kf) {
      const int cc0 = kf * 4 + lg;
      const int cc1 = 16 + kf * 4 + lg;
      const s16x8 k00 = *(const s16x8*)&Kl[cc0 * 256 + l15 * 8];
      const s16x8 k01 = *(const s16x8*)&Kl[cc0 * 256 + (16 + l15) * 8];
      const s16x8 k10 = *(const s16x8*)&Kl[cc1 * 256 + l15 * 8];
      const s16x8 k11 = *(const s16x8*)&Kl[cc1 * 256 + (16 + l15) * 8];
      s00 = __builtin_amdgcn_mfma_f32_16x16x32_bf16(k00, qf0[kf], s00, 0, 0, 0);
      s01 = __builtin_amdgcn_mfma_f32_16x16x32_bf16(k01, qf0[kf], s01, 0, 0, 0);
      s10 = __builtin_amdgcn_mfma_f32_16x16x32_bf16(k10, qf1[kf], s10, 0, 0, 0);
      s11 = __builtin_amdgcn_mfma_f32_16x16x32_bf16(k11, qf1[kf], s11, 0, 0, 0);
    }

    // ---- mask (full-tile fast path)
    float v0[8], v1[8];
    if (kb + 32 <= q0w) {
      #pragma unroll
      for (int j = 0; j < 4; ++j) {
        v0[j] = s00[j]; v0[4 + j] = s01[j];
        v1[j] = s10[j]; v1[4 + j] = s11[j];
      }
    } else {
      #pragma unroll
      for (int j = 0; j < 4; ++j) {
        const int klo = kb + lg * 4 + j, khi = klo + 16;
        v0[j]     = (klo <= q) ? s00[j] : -1e30f;
        v0[4 + j] = (khi <= q) ? s01[j] : -1e30f;
        v1[j]     = (klo <= q) ? s10[j] : -1e30f;
        v1[4 + j] = (khi <= q) ? s11[j] : -1e30f;
      }
    }
    // ---- tile max per comp
    float tm0 = fmaxf(fmaxf(fmaxf(v0[0],v0[1]),fmaxf(v0[2],v0[3])),
                      fmaxf(fmaxf(v0[4],v0[5]),fmaxf(v0[6],v0[7])));
    float tm1 = fmaxf(fmaxf(fmaxf(v1[0],v1[1]),fmaxf(v1[2],v1[3])),
                      fmaxf(fmaxf(v1[4],v1[5]),fmaxf(v1[6],v1[7])));
    tm0 = fmaxf(tm0, __shfl_xor(tm0, 16)); tm0 = fmaxf(tm0, __shfl_xor(tm0, 32));
    tm1 = fmaxf(tm1, __shfl_xor(tm1, 16)); tm1 = fmaxf(tm1, __shfl_xor(tm1, 32));

    // ---- defer-max rescale (rare)
    const bool need = (tm0 > mrun0 + RESCALE_THR) || (tm1 > mrun1 + RESCALE_THR);
    if (__any(need)) {
      const float mn0 = fmaxf(mrun0, tm0), mn1 = fmaxf(mrun1, tm1);
      const float fac0 = __expf(mrun0 - mn0), fac1 = __expf(mrun1 - mn1);
      mrun0 = mn0; mrun1 = mn1;
      lrun0 *= fac0; lrun1 *= fac1;
      #pragma unroll
      for (int jj = 0; jj < 4; ++jj) {
        const float fr0 = __shfl(fac0, lg * 4 + jj);
        const float fr1 = __shfl(fac1, lg * 4 + jj);
        #pragma unroll
        for (int nf = 0; nf < 16; ++nf) { oacc0[nf][jj] *= fr0; oacc1[nf][jj] *= fr1; }
      }
    }

    // ---- P = exp(v - mrun); pack via v_cvt_pk_bf16_f32 -> per-wave LDS transpose
    {
      float e0[8], e1[8];
      #pragma unroll
      for (int j = 0; j < 8; ++j) {
        e0[j] = __expf(v0[j] - mrun0);
        e1[j] = __expf(v1[j] - mrun1);
      }
      lrun0 += ((e0[0]+e0[1])+(e0[2]+e0[3])) + ((e0[4]+e0[5])+(e0[6]+e0[7]));
      lrun1 += ((e1[0]+e1[1])+(e1[2]+e1[3])) + ((e1[4]+e1[5])+(e1[6]+e1[7]));
      uint2 lo0, hi0, lo1, hi1;
      lo0.x = cvtpk(e0[0], e0[1]); lo0.y = cvtpk(e0[2], e0[3]);
      hi0.x = cvtpk(e0[4], e0[5]); hi0.y = cvtpk(e0[6], e0[7]);
      lo1.x = cvtpk(e1[0], e1[1]); lo1.y = cvtpk(e1[2], e1[3]);
      hi1.x = cvtpk(e1[4], e1[5]); hi1.y = cvtpk(e1[6], e1[7]);
      *(uint2*)&pl0[l15 * 40 + lg * 4]      = lo0;
      *(uint2*)&pl0[l15 * 40 + 16 + lg * 4] = hi0;
      *(uint2*)&pl1[l15 * 40 + lg * 4]      = lo1;
      *(uint2*)&pl1[l15 * 40 + 16 + lg * 4] = hi1;
    }
    asm volatile("s_waitcnt lgkmcnt(0)" ::: "memory");
    __builtin_amdgcn_sched_barrier(0);

    // ---- PV from LDS V tile (conflict-free layout)
    const s16x8 pa0 = *(const s16x8*)&pl0[l15 * 40 + lg * 8];
    const s16x8 pa1 = *(const s16x8*)&pl1[l15 * 40 + lg * 8];
    #pragma unroll
    for (int nf = 0; nf < 16; ++nf) {
      const s16x8 vf = *(const s16x8*)&Vl[lg * 2048 + (nf * 16 + l15) * 8];
      oacc0[nf] = __builtin_amdgcn_mfma_f32_16x16x32_bf16(pa0, vf, oacc0[nf], 0, 0, 0);
      oacc1[nf] = __builtin_amdgcn_mfma_f32_16x16x32_bf16(pa1, vf, oacc1[nf], 0, 0, 0);
    }
  }

  // ---- finalize row sums
  lrun0 += __shfl_xor(lrun0, 16); lrun0 += __shfl_xor(lrun0, 32);
  lrun1 += __shfl_xor(lrun1, 16); lrun1 += __shfl_xor(lrun1, 32);

  float li0[4], li1[4];
  #pragma unroll
  for (int jj = 0; jj < 4; ++jj) {
    li0[jj] = 1.0f / __shfl(lrun0, lg * 4 + jj);
    li1[jj] = 1.0f / __shfl(lrun1, lg * 4 + jj);
  }

  // ---- combine, RMSNorm over 256, scale, store
  float ss[4] = {0.f, 0.f, 0.f, 0.f};
  #pragma unroll
  for (int nf = 0; nf < 16; ++nf)
    #pragma unroll
    for (int jj = 0; jj < 4; ++jj) {
      const float o = oacc0[nf][jj] * li0[jj] - lam * oacc1[nf][jj] * li1[jj];
      oacc0[nf][jj] = o;
      ss[jj] += o * o;
    }
  #pragma unroll
  for (int jj = 0; jj < 4; ++jj) {
    ss[jj] += __shfl_xor(ss[jj], 1);
    ss[jj] += __shfl_xor(ss[jj], 2);
    ss[jj] += __shfl_xor(ss[jj], 4);
    ss[jj] += __shfl_xor(ss[jj], 8);
    ss[jj] = rsqrtf(ss[jj] * (1.0f / 256.0f) + 1e-5f) * OML;
  }
  #pragma unroll
  for (int nf = 0; nf < 16; ++nf) {
    const int dcol = nf * 16 + l15;
    const float sw = subln[dcol];
    #pragma unroll
    for (int jj = 0; jj < 4; ++jj) {
      const int t = q0w + lg * 4 + jj;
      attn_out[(size_t)t * HIDN + pair * VD + dcol] = f2bf(oacc0[nf][jj] * ss[jj] * sw);
    }
  }
}

extern "C" void kernel_launch(void* const* d_in, const int* in_sizes, int n_in,
                              void* d_out, int out_size, void* d_ws, size_t ws_size,
                              hipStream_t stream) {
  (void)in_sizes; (void)n_in; (void)out_size; (void)ws_size;
  const float* hs     = (const float*)d_in[0];
  const float* wqkv_w = (const float*)d_in[1];
  const float* wqkv_b = (const float*)d_in[2];
  const float* lq1    = (const float*)d_in[3];
  const float* lk1    = (const float*)d_in[4];
  const float* lq2    = (const float*)d_in[5];
  const float* lk2    = (const float*)d_in[6];
  const float* subln  = (const float*)d_in[7];
  const float* out_w  = (const float*)d_in[8];
  const float* out_b  = (const float*)d_in[9];

  unsigned short* qq       = (unsigned short*)d_ws;
  unsigned short* ctt      = qq + (size_t)TTOK * HIDN;
  unsigned short* attn_out = ctt + (size_t)4 * 1048576;
  unsigned short* hs_bf    = attn_out + (size_t)TTOK * HIDN;
  unsigned short* wqkv_bf  = hs_bf + (size_t)TTOK * HIDN;
  unsigned short* outw_bf  = wqkv_bf + (size_t)OPD * HIDN;
  float*          partial  = (float*)hs_bf;   // 2 x [2048][4096] fp32 (overlays dead bufs)

  const int nb0 = (TTOK * HIDN) >> 11;          // 4096
  const int nb1 = (OPD * HIDN) >> 11;           // 12288
  const int nb2 = (HIDN * HIDN) >> 11;          // 8192
  cvt3<<<dim3(nb0 + nb1 + nb2), 256, 0, stream>>>(
      hs, hs_bf, nb0, wqkv_w, wqkv_bf, nb1, out_w, outw_bf);

  // GEMM1: 128x192 tiles -> grid (32,16) = 512 blocks, 2 blocks/CU
  gemm1_qkv<<<dim3(OPD / 192, TTOK / 128), 256, 0, stream>>>(
      hs_bf, wqkv_bf, wqkv_b, qq, ctt);

  // Attention + combine + RMSNorm -> attn_out (bf16)
  attn_kernel<<<dim3(512), 256, 0, stream>>>(
      qq, ctt, lq1, lk1, lq2, lk2, subln, attn_out);

  // GEMM2 split-K: 256 blocks (16 x 8 x 2), each K=2048 -> fp32 partials
  gemm2_sk<<<dim3(HIDN / 256, TTOK / 256, 2), 512, 0, stream>>>(
      attn_out, outw_bf, partial, HIDN / 2, HIDN, HIDN, HIDN);

  // out = partial0 + partial1 + out_b
  reduce2<<<dim3((TTOK * HIDN) / 1024), 256, 0, stream>>>(
      partial, out_b, (float*)d_out);
}